// Round 6
// baseline (112.626 us; speedup 1.0000x reference)
//
#include <hip/hip_runtime.h>

// Problem constants (from setup_inputs): B=4, N=100000, M=64
#define B_IMGS 4
#define N_PROP 100000
#define HALF   50000          // 2 proposals per thread: n and n+HALF
#define M_GT   64

// Output layout (flat f32): decoded[B*N*4] | targets[B*N*4] | matches[B*N]
//
// NOTE (R6): kernel body is IDENTICAL to R5. kernel_launch launches it TWICE
// (idempotent) so that delta-dur_us vs R5's 89.4 us directly measures one
// kernel's duration — the dispatch never appears in the top-5 profile rows.

__global__ __launch_bounds__(256) void roihead_kernel(
    const float* __restrict__ proposals,  // [B,N,4]
    const float* __restrict__ gt,         // [B,M,4]
    const float* __restrict__ deltas,     // [B,N,4]
    float* __restrict__ out)
{
    __shared__ float4 g_s[M_GT];
    __shared__ float  ga_s[M_GT];

    const int b   = blockIdx.y;
    const int tid = threadIdx.x;

    if (tid < M_GT) {
        float4 g = reinterpret_cast<const float4*>(gt)[b * M_GT + tid];
        g_s[tid]  = g;
        ga_s[tid] = (g.z - g.x) * (g.w - g.y);  // numpy op order
    }
    __syncthreads();

    const int n = blockIdx.x * blockDim.x + tid;
    if (n >= HALF) return;

    const long pi0 = (long)b * N_PROP + n;
    const long pi1 = pi0 + HALF;

    const float4 p0 = reinterpret_cast<const float4*>(proposals)[pi0];
    const float4 p1 = reinterpret_cast<const float4*>(proposals)[pi1];

    float bv1_0 = -1.0f, bv2_0 = -1.0f; int bi_0 = 0;
    float bv1_1 = -1.0f, bv2_1 = -1.0f; int bi_1 = 0;
    float ap0, ap1;
    {
#pragma clang fp contract(off)
        ap0 = (p0.z - p0.x) * (p0.w - p0.y);
        ap1 = (p1.z - p1.x) * (p1.w - p1.y);
#pragma unroll 4
        for (int m = 0; m < M_GT; ++m) {
            const float4 g  = g_s[m];
            const float  ga = ga_s[m];
            {
                const float wx = fmaxf(fminf(g.z, p0.z) - fmaxf(g.x, p0.x), 0.0f);
                const float wy = fmaxf(fminf(g.w, p0.w) - fmaxf(g.y, p0.y), 0.0f);
                const float inter = wx * wy;
                const float uni   = (ga + ap0) - inter;
                const float a = inter * __builtin_amdgcn_rcpf(uni);  // approx iou
                if (a > bv1_0)      { bv2_0 = bv1_0; bv1_0 = a; bi_0 = m; }
                else if (a > bv2_0) { bv2_0 = a; }
            }
            {
                const float wx = fmaxf(fminf(g.z, p1.z) - fmaxf(g.x, p1.x), 0.0f);
                const float wy = fmaxf(fminf(g.w, p1.w) - fmaxf(g.y, p1.y), 0.0f);
                const float inter = wx * wy;
                const float uni   = (ga + ap1) - inter;
                const float a = inter * __builtin_amdgcn_rcpf(uni);
                if (a > bv1_1)      { bv2_1 = bv1_1; bv1_1 = a; bi_1 = m; }
                else if (a > bv2_1) { bv2_1 = a; }
            }
        }
    }

    const float4 d0 = reinterpret_cast<const float4*>(deltas)[pi0];
    const float4 d1 = reinterpret_cast<const float4*>(deltas)[pi1];

    float4* out4 = reinterpret_cast<float4*>(out);
    const long BN = (long)B_IMGS * N_PROP;

#pragma unroll
    for (int v = 0; v < 2; ++v) {
        const float4 p  = v ? p1 : p0;
        const float4 d  = v ? d1 : d0;
        const float  ap = v ? ap1 : ap0;
        int          bi = v ? bi_1 : bi_0;
        const float bv1 = v ? bv1_1 : bv1_0;
        const float bv2 = v ? bv2_1 : bv2_0;
        const long   pi = v ? pi1 : pi0;

        float exact_v;
        {
#pragma clang fp contract(off)
            // Ambiguous: a real runner-up within the safety margin.
            const bool ambig = (bv2 > 0.0f) && ((bv1 - bv2) <= 2e-6f * bv1);
            if (ambig) {
                // Exact-div argmax, first-max-wins — replicates numpy bit-for-bit.
                float bv = -1.0f; int nbi = 0;
                for (int m = 0; m < M_GT; ++m) {
                    const float4 g  = g_s[m];
                    const float wx = fmaxf(fminf(g.z, p.z) - fmaxf(g.x, p.x), 0.0f);
                    const float wy = fmaxf(fminf(g.w, p.w) - fmaxf(g.y, p.y), 0.0f);
                    const float inter = wx * wy;
                    const float iou = inter / ((ga_s[m] + ap) - inter);
                    if (iou > bv) { bv = iou; nbi = m; }
                }
                bi = nbi;
            }
            // One exact IEEE div: matched_val of the winner (for the 0.5 test).
            const float4 g  = g_s[bi];
            const float wx = fmaxf(fminf(g.z, p.z) - fmaxf(g.x, p.x), 0.0f);
            const float wy = fmaxf(fminf(g.w, p.w) - fmaxf(g.y, p.y), 0.0f);
            const float inter = wx * wy;
            exact_v = inter / ((ga_s[bi] + ap) - inter);
        }

        const int match = (exact_v < 0.5f) ? -1 : bi;  // FG==BG==0.5: BETWEEN dead

        // ---- BoxCoder.encode against matched (clamped) gt ----
        const float4 mg = g_s[match < 0 ? 0 : match];
        const float aw = p.z - p.x;
        const float ah = p.w - p.y;
        const float ax = p.x + 0.5f * aw;
        const float ay = p.y + 0.5f * ah;
        const float gw = fmaxf(mg.z - mg.x, 1.0f);
        const float gh = fmaxf(mg.w - mg.y, 1.0f);
        const float gx = mg.x + 0.5f * gw;
        const float gy = mg.y + 0.5f * gh;

        float4 tgt;
        tgt.x = ((gx - ax) / aw) / 0.1f;
        tgt.y = ((gy - ay) / ah) / 0.1f;
        tgt.z = logf(gw / aw) / 0.2f;
        tgt.w = logf(gh / ah) / 0.2f;

        // ---- BoxCoder.decode for predicted deltas ----
        const float sx = d.x * 0.1f;
        const float sy = d.y * 0.1f;
        const float sw = d.z * 0.2f;
        const float sh = d.w * 0.2f;
        const float cx = ax + sx * aw;
        const float cy = ay + sy * ah;
        const float w2 = expf(sw) * aw;
        const float h2 = expf(sh) * ah;

        float4 dec;
        dec.x = cx - 0.5f * w2;
        dec.y = cy - 0.5f * h2;
        dec.z = cx + 0.5f * w2;
        dec.w = cy + 0.5f * h2;

        out4[pi] = dec;                       // decoded
        out4[BN + pi] = tgt;                  // targets
        out[2 * BN * 4 + pi] = (float)match;  // matches as f32
    }
}

extern "C" void kernel_launch(void* const* d_in, const int* in_sizes, int n_in,
                              void* d_out, int out_size, void* d_ws, size_t ws_size,
                              hipStream_t stream) {
    const float* proposals = (const float*)d_in[0];
    const float* gt        = (const float*)d_in[1];
    const float* deltas    = (const float*)d_in[2];
    float* out = (float*)d_out;

    dim3 block(256);
    dim3 grid((HALF + 255) / 256, B_IMGS);
    // Launched TWICE deliberately (idempotent): delta-dur_us vs the R5 run
    // measures one kernel's duration directly. See theory note above.
    roihead_kernel<<<grid, block, 0, stream>>>(proposals, gt, deltas, out);
    roihead_kernel<<<grid, block, 0, stream>>>(proposals, gt, deltas, out);
}

// Round 7
// 86.349 us; speedup vs baseline: 1.3043x; 1.3043x over previous
//
#include <hip/hip_runtime.h>

// Problem constants (from setup_inputs): B=4, N=100000, M=64
#define B_IMGS 4
#define N_PROP 100000
#define M_GT   64

// Output layout (flat f32): decoded[B*N*4] | targets[B*N*4] | matches[B*N]
//
// R7: hot loop reads gt boxes via WAVE-UNIFORM global loads (blockIdx.y +
// loop counter only) -> compiler emits s_load into SGPRs through the scalar
// cache: no LDS b128, no lgkm-dependent chain head, prefetched by unroll-8.
// LDS holds only the 64 precomputed gt areas (ds_read_b32 per m).
// 1 proposal/thread -> 6256 waves (6.1/SIMD) for latency hiding.
// IoU math identical to R5 (rcp + top-2 + exact-div fallback, first-max-wins).

__global__ __launch_bounds__(256) void roihead_kernel(
    const float* __restrict__ proposals,  // [B,N,4]
    const float* __restrict__ gt,         // [B,M,4]
    const float* __restrict__ deltas,     // [B,N,4]
    float* __restrict__ out)
{
    __shared__ float ga_s[M_GT];

    const int b   = blockIdx.y;
    const int tid = threadIdx.x;
    const float4* __restrict__ gt4 = reinterpret_cast<const float4*>(gt) + b * M_GT;

    if (tid < M_GT) {
        const float4 g = gt4[tid];
        ga_s[tid] = (g.z - g.x) * (g.w - g.y);  // numpy op order
    }
    __syncthreads();

    const int n = blockIdx.x * blockDim.x + tid;
    if (n >= N_PROP) return;

    const long pi = (long)b * N_PROP + n;
    const float4 p = reinterpret_cast<const float4*>(proposals)[pi];

    float bv1 = -1.0f, bv2 = -1.0f; int bi = 0;
    float ap;
    {
#pragma clang fp contract(off)
        ap = (p.z - p.x) * (p.w - p.y);
#pragma unroll 8
        for (int m = 0; m < M_GT; ++m) {
            const float4 g  = gt4[m];   // wave-uniform -> s_load (scalar cache)
            const float  ga = ga_s[m];
            const float wx = fmaxf(fminf(g.z, p.z) - fmaxf(g.x, p.x), 0.0f);
            const float wy = fmaxf(fminf(g.w, p.w) - fmaxf(g.y, p.y), 0.0f);
            const float inter = wx * wy;
            const float uni   = (ga + ap) - inter;
            const float a = inter * __builtin_amdgcn_rcpf(uni);  // approx iou
            if (a > bv1)      { bv2 = bv1; bv1 = a; bi = m; }    // first-max-wins
            else if (a > bv2) { bv2 = a; }
        }
    }

    float exact_v;
    {
#pragma clang fp contract(off)
        // Ambiguous: a real runner-up within the rcp safety margin.
        const bool ambig = (bv2 > 0.0f) && ((bv1 - bv2) <= 2e-6f * bv1);
        if (ambig) {
            // Exact-div argmax, first-max-wins — replicates numpy bit-for-bit.
            float bv = -1.0f; int nbi = 0;
            for (int m = 0; m < M_GT; ++m) {
                const float4 g = gt4[m];
                const float wx = fmaxf(fminf(g.z, p.z) - fmaxf(g.x, p.x), 0.0f);
                const float wy = fmaxf(fminf(g.w, p.w) - fmaxf(g.y, p.y), 0.0f);
                const float inter = wx * wy;
                const float iou = inter / ((ga_s[m] + ap) - inter);
                if (iou > bv) { bv = iou; nbi = m; }
            }
            bi = nbi;
        }
        // One exact IEEE div: matched_val of the winner (for the 0.5 test).
        const float4 g = gt4[bi];
        const float wx = fmaxf(fminf(g.z, p.z) - fmaxf(g.x, p.x), 0.0f);
        const float wy = fmaxf(fminf(g.w, p.w) - fmaxf(g.y, p.y), 0.0f);
        const float inter = wx * wy;
        exact_v = inter / ((ga_s[bi] + ap) - inter);
    }

    const int match = (exact_v < 0.5f) ? -1 : bi;  // FG==BG==0.5: BETWEEN dead

    // ---- BoxCoder.encode against matched (clamped) gt ----
    const float4 mg = gt4[match < 0 ? 0 : match];
    const float aw = p.z - p.x;
    const float ah = p.w - p.y;
    const float ax = p.x + 0.5f * aw;
    const float ay = p.y + 0.5f * ah;
    const float gw = fmaxf(mg.z - mg.x, 1.0f);
    const float gh = fmaxf(mg.w - mg.y, 1.0f);
    const float gx = mg.x + 0.5f * gw;
    const float gy = mg.y + 0.5f * gh;

    float4 tgt;
    tgt.x = ((gx - ax) / aw) / 0.1f;
    tgt.y = ((gy - ay) / ah) / 0.1f;
    tgt.z = logf(gw / aw) / 0.2f;
    tgt.w = logf(gh / ah) / 0.2f;

    // ---- BoxCoder.decode for predicted deltas ----
    const float4 d = reinterpret_cast<const float4*>(deltas)[pi];
    const float sx = d.x * 0.1f;
    const float sy = d.y * 0.1f;
    const float sw = d.z * 0.2f;
    const float sh = d.w * 0.2f;
    const float cx = ax + sx * aw;
    const float cy = ay + sy * ah;
    const float w2 = expf(sw) * aw;
    const float h2 = expf(sh) * ah;

    float4 dec;
    dec.x = cx - 0.5f * w2;
    dec.y = cy - 0.5f * h2;
    dec.z = cx + 0.5f * w2;
    dec.w = cy + 0.5f * h2;

    float4* out4 = reinterpret_cast<float4*>(out);
    const long BN = (long)B_IMGS * N_PROP;
    out4[pi] = dec;                       // decoded
    out4[BN + pi] = tgt;                  // targets
    out[2 * BN * 4 + pi] = (float)match;  // matches as f32
}

extern "C" void kernel_launch(void* const* d_in, const int* in_sizes, int n_in,
                              void* d_out, int out_size, void* d_ws, size_t ws_size,
                              hipStream_t stream) {
    const float* proposals = (const float*)d_in[0];
    const float* gt        = (const float*)d_in[1];
    const float* deltas    = (const float*)d_in[2];
    float* out = (float*)d_out;

    dim3 block(256);
    dim3 grid((N_PROP + 255) / 256, B_IMGS);
    roihead_kernel<<<grid, block, 0, stream>>>(proposals, gt, deltas, out);
}